// Round 8
// baseline (79.831 us; speedup 1.0000x reference)
//
#include <hip/hip_runtime.h>
#include <hip/hip_bf16.h>
#include <cstddef>
#include <cstdint>

// LinearAttention fused pipeline, MI355X gfx950.
// x:[16,64,64,128] f32, w_qkv:[128,384], w_out:[128,128], b_out/g_ln/b_ln:[128]
// Pipeline (6 kernels, all GEMM inputs bf16):
//   K1 k_transpose_wqkv: w_qkv -> w_qkv^T bf16
//   K2 k_xbf: x f32 -> xbf bf16 [65536][128] (streaming; control for x-read BW)
//   K3 k_q_soft: q GEMM from xbf + softmax(d)*scale -> qs bf16 (PACKED dword
//      stores, within-head k-permuted layout d'=2*(d&15)+(d>>4))
//   K4 k_kv_ctx: k,v GEMMs from xbf + exp(k) -> LDS transpose -> per-head
//      ctx[32][32] partial MFMA + ksum via MFMA(ones).
//   K5 k_weff64: reduce ctx partials, ctxn=ctx/ksum, W_eff^T (k-dim stored
//      with the SAME permutation as qs -> dot products unchanged).
//   K6 k_out_ln: out = LN( qs @ W_eff[b] + b_out ). bf16 in, 5.5TB/s. Leave.
// Evidence R1-R7: f32-x readers all ~1TB/s effective; bf16-input out_ln hits
// 5.5TB/s with same structure => convert x once, feed everything bf16.

typedef __attribute__((ext_vector_type(8))) short short8_t;
typedef __attribute__((ext_vector_type(4))) float f32x4;

#define SCALE_Q 0.17677669529663687f
#define EPS_LN 1e-5f

__device__ __forceinline__ unsigned short f2bf(float f) {
  union { float f; unsigned u; } v; v.f = f;
  unsigned r = (v.u + 0x7FFFu + ((v.u >> 16) & 1u)) >> 16;
  return (unsigned short)r;
}
__device__ __forceinline__ float bf2f(unsigned short u) {
  union { float f; unsigned u; } v; v.u = ((unsigned)u) << 16;
  return v.f;
}
// pack 2 f32 -> 2 bf16 (truncate): low16 = f0, high16 = f1
__device__ __forceinline__ unsigned pack2(float f0, float f1) {
  union { float f; unsigned u; } a, b; a.f = f0; b.f = f1;
  return __builtin_amdgcn_perm(b.u, a.u, 0x07060302);
}

// ---------------- K1: transpose + bf16 convert w_qkv [128][384] -> [384][128]
__global__ void k_transpose_wqkv(const float* __restrict__ w,
                                 unsigned short* __restrict__ wT) {
  int c = blockIdx.x * 4 + (threadIdx.x >> 6);   // 96 blocks -> c < 384
  int l = threadIdx.x & 63;
  float f0 = w[(size_t)(2 * l) * 384 + c];
  float f1 = w[(size_t)(2 * l + 1) * 384 + c];
  ((unsigned*)(wT + (size_t)c * 128))[l] = pack2(f0, f1);
}

// ---------------- K2: x f32 -> bf16 streaming convert (truncation)
// grid 2048: 2048*256*4 float4 = 2097152 = 65536*128/4.
__global__ void k_xbf(const float* __restrict__ x, unsigned* __restrict__ xbf) {
  const float4* x4 = (const float4*)x;
  uint2* o = (uint2*)xbf;
  int base = blockIdx.x * 1024 + threadIdx.x;
  float4 v[4];
#pragma unroll
  for (int it = 0; it < 4; ++it) v[it] = x4[base + it * 256];
#pragma unroll
  for (int it = 0; it < 4; ++it) {
    uint2 p;
    p.x = pack2(v[it].x, v[it].y);
    p.y = pack2(v[it].z, v[it].w);
    o[base + it * 256] = p;
  }
}

// ---------------- K3: q GEMM (bf16 A) + softmax(d) -> qs packed dwords
// 64-token tiles, grid 1024, LDS 34KB -> 4 blocks/CU, one barrier.
// qs row layout: index wc*64+hg*32+2*lr+{0,1} = permuted d'=2*(d&15)+(d>>4).
__global__ __launch_bounds__(256, 4)
void k_q_soft(const unsigned short* __restrict__ xbf, const unsigned short* __restrict__ wT,
              unsigned short* __restrict__ qs) {
  __shared__ short Bq[128][136];
  int tid = threadIdx.x;
  int rowBase = blockIdx.x * 64;

  { // stage Bq (wT part 0), coalesced
#pragma unroll
    for (int i = 0; i < 8; ++i) {
      int idx = i * 256 + tid;
      int n = idx >> 4;
      int k8 = (idx & 15) << 3;
      *(short8_t*)&Bq[n][k8] = *(const short8_t*)(wT + (size_t)n * 128 + k8);
    }
  }

  int lane = tid & 63;
  int wv = tid >> 6;
  int wr = wv >> 1, wc = wv & 1;
  int lr = lane & 15;
  int kg = lane >> 4;

  // A fragments direct from xbf (bf16, no conversion)
  short8_t abf[4][2];  // [kk][mf]
  {
    const unsigned short* ap = xbf + (size_t)(rowBase + wr * 32 + lr) * 128 + kg * 8;
#pragma unroll
    for (int mf = 0; mf < 2; ++mf)
#pragma unroll
      for (int kk = 0; kk < 4; ++kk)
        abf[kk][mf] = *(const short8_t*)(ap + (size_t)mf * 16 * 128 + kk * 32);
  }
  __syncthreads();

  f32x4 acc[2][4] = {};
#pragma unroll
  for (int kk = 0; kk < 4; ++kk) {
    short8_t bf[4];
#pragma unroll
    for (int nf = 0; nf < 4; ++nf)
      bf[nf] = *(const short8_t*)&Bq[wc * 64 + nf * 16 + lr][kk * 32 + kg * 8];
#pragma unroll
    for (int mf = 0; mf < 2; ++mf)
#pragma unroll
      for (int nf = 0; nf < 4; ++nf)
        acc[mf][nf] = __builtin_amdgcn_mfma_f32_16x16x32_bf16(abf[kk][mf], bf[nf], acc[mf][nf], 0, 0, 0);
  }

  // softmax over d(32) per (row, head); no max pass (|q| <= ~4)
#pragma unroll
  for (int hg = 0; hg < 2; ++hg) {
#pragma unroll
    for (int mf = 0; mf < 2; ++mf) {
#pragma unroll
      for (int j = 0; j < 4; ++j) {
        float e0 = __expf(acc[mf][hg * 2][j]);
        float e1 = __expf(acc[mf][hg * 2 + 1][j]);
        float s = e0 + e1;
#pragma unroll
        for (int d = 1; d < 16; d <<= 1) s += __shfl_xor(s, d, 64);
        float inv = SCALE_Q / s;
        int tok = rowBase + wr * 32 + mf * 16 + kg * 4 + j;
        // packed dword store, permuted within-head index 2*lr (+1)
        *(unsigned*)&qs[(size_t)tok * 128 + wc * 64 + hg * 32 + 2 * lr] =
            pack2(e0 * inv, e1 * inv);
      }
    }
  }
}

// ---------------- K4: k+v GEMMs (bf16 A) + in-tile ctx partial + MFMA ksum
// grid 512 (one per 128-token tile). ctxp[blk][h][32][32] f32, ksump[blk][128].
__global__ __launch_bounds__(256, 2)
void k_kv_ctx(const unsigned short* __restrict__ xbf, const unsigned short* __restrict__ wT,
              float* __restrict__ ctxp, float* __restrict__ ksump) {
  __shared__ short Bk[128][136];  // k weights; later reused as ekT[d][token]
  __shared__ short Bv[128][136];  // v weights; later reused as vT[e][token]

  int tid = threadIdx.x;
  int rb = blockIdx.x;
  int rowBase = rb * 128;

  { // stage Bk, Bv from wT parts 1 and 2 (coalesced)
    const unsigned short* wk = wT + (size_t)1 * 128 * 128;
    const unsigned short* wv2 = wT + (size_t)2 * 128 * 128;
#pragma unroll
    for (int i = 0; i < 8; ++i) {
      int idx = i * 256 + tid;
      int n = idx >> 4;
      int k8 = (idx & 15) << 3;
      *(short8_t*)&Bk[n][k8] = *(const short8_t*)(wk + (size_t)n * 128 + k8);
      *(short8_t*)&Bv[n][k8] = *(const short8_t*)(wv2 + (size_t)n * 128 + k8);
    }
  }

  int lane = tid & 63;
  int wv = tid >> 6;
  int wr = wv >> 1, wc = wv & 1;
  int lr = lane & 15;
  int kg = lane >> 4;

  // A fragments direct from xbf (bf16); reused by both GEMMs
  short8_t abf[4][4];  // [kk][mf]
  {
    const unsigned short* ap = xbf + (size_t)(rowBase + wr * 64 + lr) * 128 + kg * 8;
#pragma unroll
    for (int mf = 0; mf < 4; ++mf)
#pragma unroll
      for (int kk = 0; kk < 4; ++kk)
        abf[kk][mf] = *(const short8_t*)(ap + (size_t)mf * 16 * 128 + kk * 32);
  }
  __syncthreads();  // Bk/Bv staged

  // k GEMM -> exp -> packed bf16 (4 tokens per uint2)
  uint2 ekp[4][4], vp[4][4];
  {
    f32x4 acc[4][4] = {};
#pragma unroll
    for (int kk = 0; kk < 4; ++kk) {
      short8_t bf[4];
#pragma unroll
      for (int nf = 0; nf < 4; ++nf)
        bf[nf] = *(const short8_t*)&Bk[wc * 64 + nf * 16 + lr][kk * 32 + kg * 8];
#pragma unroll
      for (int mf = 0; mf < 4; ++mf)
#pragma unroll
        for (int nf = 0; nf < 4; ++nf)
          acc[mf][nf] = __builtin_amdgcn_mfma_f32_16x16x32_bf16(abf[kk][mf], bf[nf], acc[mf][nf], 0, 0, 0);
    }
#pragma unroll
    for (int mf = 0; mf < 4; ++mf)
#pragma unroll
      for (int nf = 0; nf < 4; ++nf) {
        ekp[mf][nf].x = pack2(__expf(acc[mf][nf][0]), __expf(acc[mf][nf][1]));
        ekp[mf][nf].y = pack2(__expf(acc[mf][nf][2]), __expf(acc[mf][nf][3]));
      }
  }
  // v GEMM -> packed bf16
  {
    f32x4 acc[4][4] = {};
#pragma unroll
    for (int kk = 0; kk < 4; ++kk) {
      short8_t bf[4];
#pragma unroll
      for (int nf = 0; nf < 4; ++nf)
        bf[nf] = *(const short8_t*)&Bv[wc * 64 + nf * 16 + lr][kk * 32 + kg * 8];
#pragma unroll
      for (int mf = 0; mf < 4; ++mf)
#pragma unroll
        for (int nf = 0; nf < 4; ++nf)
          acc[mf][nf] = __builtin_amdgcn_mfma_f32_16x16x32_bf16(abf[kk][mf], bf[nf], acc[mf][nf], 0, 0, 0);
    }
#pragma unroll
    for (int mf = 0; mf < 4; ++mf)
#pragma unroll
      for (int nf = 0; nf < 4; ++nf) {
        vp[mf][nf].x = pack2(acc[mf][nf][0], acc[mf][nf][1]);
        vp[mf][nf].y = pack2(acc[mf][nf][2], acc[mf][nf][3]);
      }
  }
  __syncthreads();  // all waves done reading Bk/Bv

  // transposed LDS write: ekT[channel][token], vT[channel][token]
  short (*ekT)[136] = Bk;
  short (*vT)[136] = Bv;
#pragma unroll
  for (int mf = 0; mf < 4; ++mf) {
    int t0 = wr * 64 + mf * 16 + kg * 4;  // 4 consecutive tokens
#pragma unroll
    for (int nf = 0; nf < 4; ++nf) {
      int col = wc * 64 + nf * 16 + lr;
      *(uint2*)&ekT[col][t0] = ekp[mf][nf];
      *(uint2*)&vT[col][t0] = vp[mf][nf];
    }
  }
  __syncthreads();

  // per-head ctx MFMA (wave = head) + ksum via MFMA with ones-vector
  {
    int h = wv;
    union { unsigned u[4]; short8_t s; } ones;
#pragma unroll
    for (int i = 0; i < 4; ++i) ones.u[i] = 0x3F803F80u;  // bf16 1.0 x2

    f32x4 c2[2][2] = {};
    f32x4 ks2[2] = {};
#pragma unroll
    for (int kk = 0; kk < 4; ++kk) {
      short8_t a2[2], b2[2];
#pragma unroll
      for (int m2 = 0; m2 < 2; ++m2)
        a2[m2] = *(const short8_t*)&ekT[h * 32 + m2 * 16 + lr][kk * 32 + kg * 8];
#pragma unroll
      for (int n2 = 0; n2 < 2; ++n2)
        b2[n2] = *(const short8_t*)&vT[h * 32 + n2 * 16 + lr][kk * 32 + kg * 8];
#pragma unroll
      for (int m2 = 0; m2 < 2; ++m2) {
#pragma unroll
        for (int n2 = 0; n2 < 2; ++n2)
          c2[m2][n2] = __builtin_amdgcn_mfma_f32_16x16x32_bf16(a2[m2], b2[n2], c2[m2][n2], 0, 0, 0);
        ks2[m2] = __builtin_amdgcn_mfma_f32_16x16x32_bf16(a2[m2], ones.s, ks2[m2], 0, 0, 0);
      }
    }
    float* cp = ctxp + ((size_t)rb * 4 + h) * 1024;
#pragma unroll
    for (int m2 = 0; m2 < 2; ++m2)
#pragma unroll
      for (int n2 = 0; n2 < 2; ++n2)
#pragma unroll
        for (int j = 0; j < 4; ++j)
          cp[(m2 * 16 + kg * 4 + j) * 32 + n2 * 16 + lr] = c2[m2][n2][j];
    if (lr == 0) {  // every col of ks2 identical
#pragma unroll
      for (int m2 = 0; m2 < 2; ++m2)
#pragma unroll
        for (int j = 0; j < 4; ++j)
          ksump[(size_t)rb * 128 + h * 32 + m2 * 16 + kg * 4 + j] = ks2[m2][j];
    }
  }
}

// ---------------- K5: per (b,h) reduce partials + build W_eff^T cols
// grid 64. Stores k-dim PERMUTED to match qs: new index = h*32 + 2*dd + dg.
__global__ __launch_bounds__(256, 4)
void k_weff64(const float* __restrict__ ctxp, const float* __restrict__ ksump,
              const float* __restrict__ wout, unsigned short* __restrict__ weffT) {
  __shared__ float wo[32][128];  // wout rows h*32+e
  __shared__ float cn[32][32];   // ctxn[d][e]
  __shared__ float ksh[32];
  int tid = threadIdx.x;
  int b = blockIdx.x >> 2, h = blockIdx.x & 3;

#pragma unroll
  for (int i = 0; i < 16; ++i) {
    int idx = i * 256 + tid;
    int e = idx >> 7, jj = idx & 127;
    wo[e][jj] = wout[(h * 32 + e) * 128 + jj];
  }
  if (tid < 32) {
    float s = 0;
    for (int c = 0; c < 32; ++c)
      s += ksump[(size_t)(b * 32 + c) * 128 + h * 32 + tid];
    ksh[tid] = s;
  }
  __syncthreads();
#pragma unroll
  for (int i = 0; i < 4; ++i) {
    int idx = i * 256 + tid;
    int d = idx >> 5;
    float s = 0;
    for (int c = 0; c < 32; ++c)
      s += ctxp[((size_t)(b * 32 + c) * 4 + h) * 1024 + idx];
    cn[d][idx & 31] = s / ksh[d];
  }
  __syncthreads();

  // thread (j, half8): 16 dots -> 8 packed dwords (d'=2*dd+dg), 2x uint4 store
  int j = tid >> 1, h8 = (tid & 1) * 8;
  unsigned pk[8];
#pragma unroll
  for (int t = 0; t < 8; ++t) {
    int dd = h8 + t;
    float s0 = 0, s1 = 0;
#pragma unroll
    for (int e = 0; e < 32; ++e) {
      float w = wo[e][j];
      s0 += cn[dd][e] * w;
      s1 += cn[16 + dd][e] * w;
    }
    pk[t] = pack2(s0, s1);  // low=dg0(d=dd), high=dg1(d=16+dd) -> idx 2*dd+dg
  }
  unsigned* outp = (unsigned*)(weffT + (size_t)b * 16384 + j * 128 + h * 32 + 2 * h8);
  *(uint4*)outp = make_uint4(pk[0], pk[1], pk[2], pk[3]);
  *(uint4*)(outp + 4) = make_uint4(pk[4], pk[5], pk[6], pk[7]);
}

// ---------------- K6: out = LN( qs @ W_eff[b] + b_out ) — 5.5 TB/s, leave as is
__global__ __launch_bounds__(256, 2)
void k_out_ln(const unsigned short* __restrict__ qs, const unsigned short* __restrict__ weffT,
              const float* __restrict__ b_out, const float* __restrict__ g_ln,
              const float* __restrict__ b_ln, float* __restrict__ out) {
  int tid = threadIdx.x;
  int rowBase = blockIdx.x * 128;
  int b = rowBase >> 12;
  int lane = tid & 63;
  int w = tid >> 6;
  int lr = lane & 15;
  int kg = lane >> 4;

  const unsigned short* bb = weffT + (size_t)b * 16384;

  short8_t a[2][4];  // [mf][kk]
  {
    const unsigned short* ap = qs + (size_t)(rowBase + w * 32 + lr) * 128 + kg * 8;
#pragma unroll
    for (int mf = 0; mf < 2; ++mf)
#pragma unroll
      for (int kk = 0; kk < 4; ++kk)
        a[mf][kk] = *(const short8_t*)(ap + (size_t)mf * 16 * 128 + kk * 32);
  }

  f32x4 acc[2][8] = {};
#pragma unroll
  for (int kk = 0; kk < 4; ++kk) {
    short8_t bf[8];
#pragma unroll
    for (int nf = 0; nf < 8; ++nf)
      bf[nf] = *(const short8_t*)(bb + (size_t)(nf * 16 + lr) * 128 + kk * 32 + kg * 8);
#pragma unroll
    for (int mf = 0; mf < 2; ++mf)
#pragma unroll
      for (int nf = 0; nf < 8; ++nf)
        acc[mf][nf] = __builtin_amdgcn_mfma_f32_16x16x32_bf16(a[mf][kk], bf[nf], acc[mf][nf], 0, 0, 0);
  }

  float bo[8], gl[8], bl[8];
#pragma unroll
  for (int nf = 0; nf < 8; ++nf) {
    int c = nf * 16 + lr;
    bo[nf] = b_out[c]; gl[nf] = g_ln[c]; bl[nf] = b_ln[c];
  }
#pragma unroll
  for (int mf = 0; mf < 2; ++mf)
#pragma unroll
    for (int nf = 0; nf < 8; ++nf)
#pragma unroll
      for (int j = 0; j < 4; ++j) acc[mf][nf][j] += bo[nf];

#pragma unroll
  for (int mf = 0; mf < 2; ++mf) {
    float s[4] = {0, 0, 0, 0}, q[4] = {0, 0, 0, 0};
#pragma unroll
    for (int nf = 0; nf < 8; ++nf)
#pragma unroll
      for (int j = 0; j < 4; ++j) {
        float v = acc[mf][nf][j];
        s[j] += v; q[j] += v * v;
      }
#pragma unroll
    for (int j = 0; j < 4; ++j) {
#pragma unroll
      for (int d = 1; d < 16; d <<= 1) {
        s[j] += __shfl_xor(s[j], d, 64);
        q[j] += __shfl_xor(q[j], d, 64);
      }
    }
#pragma unroll
    for (int j = 0; j < 4; ++j) {
      float mean = s[j] * (1.0f / 128.0f);
      float var = q[j] * (1.0f / 128.0f) - mean * mean;
      float rstd = rsqrtf(var + EPS_LN);
      size_t ro = (size_t)(rowBase + w * 32 + mf * 16 + kg * 4 + j) * 128;
#pragma unroll
      for (int nf = 0; nf < 8; ++nf)
        out[ro + nf * 16 + lr] = (acc[mf][nf][j] - mean) * rstd * gl[nf] + bl[nf];
    }
  }
}

extern "C" void kernel_launch(void* const* d_in, const int* in_sizes, int n_in,
                              void* d_out, int out_size, void* d_ws, size_t ws_size,
                              hipStream_t stream) {
  const float* x     = (const float*)d_in[0];
  const float* w_qkv = (const float*)d_in[1];
  const float* w_out = (const float*)d_in[2];
  const float* b_out = (const float*)d_in[3];
  const float* g_ln  = (const float*)d_in[4];
  const float* b_ln  = (const float*)d_in[5];
  float* out = (float*)d_out;

  char* ws = (char*)d_ws;
  unsigned short* wqkvT = (unsigned short*)(ws + 0);          // 96 KB (128KB slot)
  unsigned short* xbf   = (unsigned short*)(ws + 131072);     // 16.78 MB [65536][128]
  float* ctxp           = (float*)(ws + 16908288);            // 8 MB [512][4][32][32]
  float* ksump          = (float*)(ws + 25296896);            // 256 KB [512][128]
  unsigned short* weffT = (unsigned short*)(ws + 25559040);   // 512 KB [16][128][128]
  unsigned short* qs    = (unsigned short*)(ws + 26083328);   // 16.78 MB [65536][128]

  k_transpose_wqkv<<<96, 256, 0, stream>>>(w_qkv, wqkvT);
  k_xbf<<<2048, 256, 0, stream>>>(x, (unsigned*)xbf);
  k_q_soft<<<1024, 256, 0, stream>>>(xbf, wqkvT, qs);
  k_kv_ctx<<<512, 256, 0, stream>>>(xbf, wqkvT, ctxp, ksump);
  k_weff64<<<64, 256, 0, stream>>>(ctxp, ksump, w_out, weffT);
  k_out_ln<<<512, 256, 0, stream>>>(qs, weffT, b_out, g_ln, b_ln, out);
}